// Round 2
// baseline (1620.005 us; speedup 1.0000x reference)
//
#include <hip/hip_runtime.h>
#include <math.h>

#define S_LEN 256
#define NCELL 8
#define HID 16
#define MEM 20
#define NB 4
#define NTHR 512
#define RSTR 2592   // ring batch stride in f16 (bank skew)
#define RP 80       // reduction row stride (floats): bank shift 16 -> 2-way

typedef _Float16 v8h __attribute__((ext_vector_type(8)));
typedef _Float16 v4h __attribute__((ext_vector_type(4)));
typedef float v4f __attribute__((ext_vector_type(4)));

__device__ __forceinline__ float sigm(float v) { return 1.0f / (1.0f + __expf(-v)); }
__device__ __forceinline__ float tanh_f(float v) { return 1.0f - 2.0f / (__expf(2.0f * v) + 1.0f); }
__device__ __forceinline__ float dot4(float4 a, float4 b) {
    return fmaf(a.x, b.x, fmaf(a.y, b.y, fmaf(a.z, b.z, a.w * b.w)));
}
__device__ __forceinline__ v4f mfma16(v8h a, v8h b, v4f c) {
    return __builtin_amdgcn_mfma_f32_16x16x32_f16(a, b, c, 0, 0, 0);
}

#define RING(b, s, k) ringH[(b) * RSTR + (s) * 128 + (k)]

// prep: W1F (163840 f16, A-frag order, verified R11) + WAF (16384, expert
// cells) + W2F (1024, W2 as 2 K-tiles) + WAGF (4096, agent [Wa_ih|Wa_hh]
// K=32 A-frags, 2 layers x 4 gate-tiles).
__global__ __launch_bounds__(256)
void prep_w(const float* __restrict__ W1, const float* __restrict__ W_hh,
            const float* __restrict__ W_ih, const float* __restrict__ b_ih,
            const float* __restrict__ b_hh, const float* __restrict__ W2,
            const float* __restrict__ Wa_ih, const float* __restrict__ Wa_hh,
            _Float16* __restrict__ W1F, _Float16* __restrict__ WAF,
            _Float16* __restrict__ W2F, _Float16* __restrict__ WAGF) {
    int idx = blockIdx.x * 256 + threadIdx.x;
    if (idx < 163840) {
        int e = idx & 7, lane = (idx >> 3) & 63, jt = (idx >> 9) & 3, t = idx >> 11;
        int m = t >> 2, kc = t & 3;
        int j = jt * 16 + (lane & 15);
        int k = kc * 32 + (lane >> 4) * 8 + e;
        W1F[idx] = (_Float16)W1[j * 2580 + m * 129 + k];
    } else if (idx < 163840 + 16384) {
        int d = idx - 163840;
        int e = d & 7, lane = (d >> 3) & 63, gate = (d >> 9) & 3, c = d >> 11;
        int m = lane & 15, k = (lane >> 4) * 8 + e;
        int row = c * 64 + gate * 16 + m;
        float v = 0.f;
        if (k < 16) v = W_hh[row * 16 + k];
        else if (k == 16) v = W_ih[row];
        else if (k == 17) v = b_ih[row] + b_hh[row];
        WAF[d] = (_Float16)v;
    } else if (idx < 163840 + 16384 + 1024) {
        int d = idx - 163840 - 16384;
        int e = d & 7, lane = (d >> 3) & 63, kc = d >> 9;
        int i = lane & 15, k = kc * 32 + (lane >> 4) * 8 + e;
        W2F[d] = (_Float16)W2[i * 64 + k];
    } else if (idx < 163840 + 16384 + 1024 + 4096) {
        int d = idx - 163840 - 16384 - 1024;
        int e = d & 7, lane = (d >> 3) & 63, jt = (d >> 9) & 3, l = d >> 11;
        int g = jt * 16 + (lane & 15);
        int k = (lane >> 4) * 8 + e;
        float v = (k < 16) ? Wa_ih[(l * 64 + g) * 16 + k]
                           : Wa_hh[(l * 64 + g) * 16 + (k - 16)];
        WAGF[d] = (_Float16)v;
    }
}

// R19: R18's register-resident W1F failed because the compiler capped VGPRs
// at 128 (occupancy heuristic) and spilled wA[44] to scratch (WRITE_SIZE
// 0.5->18.7 MB). Grid is 128 WGs on 256 CUs -> 1 WG/CU regardless, so the
// protected occupancy was worthless. Fix: amdgpu_waves_per_eu(2) -> 256 VGPR
// budget, and trim residency to 40 frags (160 VGPR); iteration 10's 4 frags
// are prefetched from L2 at the top of 2b (use is 40 MFMAs later = covered).
#define E1P(BB, V) { \
    V = b1_l[lane] \
      + red[par][1][BB][lane] + red[par][2][BB][lane] + red[par][3][BB][lane] \
      + red[par][4][BB][lane] + red[par][5][BB][lane] + red[par][6][BB][lane] \
      + red[par][7][BB][lane]; }

__global__ __attribute__((amdgpu_flat_work_group_size(NTHR, NTHR), amdgpu_waves_per_eu(2)))
void mmoe_kernel(const float* __restrict__ x, const float* __restrict__ pred0,
                 const float* __restrict__ gate0,
                 const float* __restrict__ W_ih, const float* __restrict__ W_hh,
                 const float* __restrict__ b_ih, const float* __restrict__ b_hh,
                 const float* __restrict__ W_o, const float* __restrict__ b_o,
                 const float* __restrict__ W1, const float* __restrict__ b1,
                 const float* __restrict__ W2, const float* __restrict__ b2,
                 const float* __restrict__ Wg, const float* __restrict__ bg,
                 const float* __restrict__ Wa_ih, const float* __restrict__ Wa_hh,
                 const float* __restrict__ ba_ih, const float* __restrict__ ba_hh,
                 const _Float16* __restrict__ W1F, const _Float16* __restrict__ WAF,
                 const _Float16* __restrict__ W2F, const _Float16* __restrict__ WAGF,
                 float* __restrict__ out)
{
    __shared__ __align__(16) _Float16 ringH[NB * RSTR];      // skewed ring (h rows)
    __shared__ __align__(16) _Float16 ehH[NB][40];           // [eh(16)|x|1|0..] f16
    __shared__ __align__(16) _Float16 W2F_l[2 * 512];        // ai A-frags
    __shared__ __align__(16) _Float16 WaG_l[2 * 4 * 512];    // agent A-frags
    __shared__ __align__(16) _Float16 e1B[NB][64];           // e1 f16 (ai B operand)
    __shared__ __align__(16) _Float16 agB0[NB][32];          // [inp|ah0] layer-0 B
    __shared__ __align__(16) _Float16 agB1[NB][32];          // [ah0|ah1] layer-1 B
    __shared__ float errS[NB][MEM];
    __shared__ float ba_l[2][64];
    __shared__ float b2_l[16];
    __shared__ __align__(16) float Wg_l[8][16], Wo_l[8][16];
    __shared__ float bg_l[8], bo_l[8];
    __shared__ float Werr_l[MEM * 64];
    __shared__ float b1_l[64];
    __shared__ float xS[NB][S_LEN];
    __shared__ __align__(16) float ecS[NB][HID];
    __shared__ __align__(16) float nhS[NCELL][NB][HID];      // [c][b][h]: 2-way banks
    __shared__ __align__(16) float ncS[NCELL][NB][HID];
    __shared__ float oS[NB][NCELL], predS[NB], gateS[NB][NCELL];
    __shared__ __align__(16) float acS[2][NB][HID];
    __shared__ __align__(16) float ah1S[NB][HID];            // layer-1 h, f32 (gate dot)
    __shared__ __align__(16) float glog[NB][8];
    __shared__ __align__(16) float red[2][8][NB][RP];        // stream partials (pad 80)
    __shared__ __align__(16) float red0[4][NB][RP];          // m=0 term (pad 80)
    __shared__ float errdotS[NB][64];
    __shared__ float thS[NB];

    const int tid = threadIdx.x;
    const int b0 = blockIdx.x * NB;
    const int lane = tid & 63, wv = tid >> 6;
    const int quad = lane >> 4, nn = lane & 15, bb4 = nn & 3;

    // ---- one-time staging ----
    for (int i = tid; i < 128; i += NTHR) { int l = i >> 6, g = i & 63; ba_l[l][g] = ba_ih[i] + ba_hh[i]; }
    for (int i = tid; i < 1024; i += NTHR) W2F_l[i] = W2F[i];
    for (int i = tid; i < 4096; i += NTHR) WaG_l[i] = WAGF[i];
    for (int i = tid; i < 1280; i += NTHR) { int m = i >> 6, j = i & 63; Werr_l[i] = W1[j * 2580 + m * 129 + 128]; }
    if (tid < 64) b1_l[tid] = b1[tid];
    if (tid < 16) b2_l[tid] = b2[tid];
    if (tid < 128) { int c = tid >> 4, h = tid & 15; Wg_l[c][h] = Wg[tid]; Wo_l[c][h] = W_o[tid]; }
    if (tid < 8) { bg_l[tid] = bg[tid]; bo_l[tid] = b_o[tid]; }
    for (int i = tid; i < NB * S_LEN; i += NTHR) { int b = i >> 8, s = i & 255; xS[b][s] = x[(b0 + b) * S_LEN + s]; }
    for (int i = tid; i < NB * RSTR; i += NTHR) ringH[i] = (_Float16)0.0f;
    for (int i = tid; i < 2 * 8 * NB * RP; i += NTHR) ((float*)red)[i] = 0.0f;
    for (int i = tid; i < NB * 32; i += NTHR) { ((_Float16*)agB0)[i] = (_Float16)0.0f; ((_Float16*)agB1)[i] = (_Float16)0.0f; }
    if (tid < NB * 40) {
        int n = tid / 40, k = tid % 40;
        float v = 0.f;
        if (k == 16) v = x[(b0 + n) * S_LEN + 0];
        else if (k == 17) v = 1.0f;
        ehH[n][k] = (_Float16)v;
    }
    if (tid < NB * MEM) { int b = tid / MEM, m = tid % MEM; errS[b][m] = 0.5f; }
    if (tid < NB * HID) {
        int b = tid >> 4, h = tid & 15;
        ecS[b][h] = 0.f;
        acS[0][b][h] = 0.f; acS[1][b][h] = 0.f;
        ah1S[b][h] = 0.f;
    }
    if (tid < NB) predS[tid] = pred0[b0 + tid];
    if (tid < NB * NCELL) { int b = tid >> 3, c = tid & 7; gateS[b][c] = gate0[(b0 + b) * NCELL + c]; }

    // ---- loop-invariant register A-frags ----
    const v8h* WA = (const v8h*)WAF;
    v8h aI = WA[(wv * 4 + 0) * 64 + lane];
    v8h aF = WA[(wv * 4 + 1) * 64 + lane];
    v8h aG = WA[(wv * 4 + 2) * 64 + lane];
    v8h aO = WA[(wv * 4 + 3) * 64 + lane];
    const v8h* Wb = (const v8h*)W1F;
    const int kcW = wv >> 1, jt0W = (wv & 1) * 2;
    v8h m0A = Wb[(size_t)(kcW * 4 + jt0W) * 64 + lane];
    v8h m0B = Wb[(size_t)(kcW * 4 + jt0W + 1) * 64 + lane];
    const v8h* W2Fv = (const v8h*)W2F_l;
    const v8h* WaGv = (const v8h*)WaG_l;

    // ---- R19: 40 W1F frags register-resident (160 VGPR); iteration 10
    // prefetched per-step from L2. Wave 0 loads wave-1's copy (harmless,
    // uniform code); it never uses wA.
    const int ktS = (wv >= 1) ? (wv - 1) * 11 : 0;
    v8h wA[40];
    #pragma unroll
    for (int i = 0; i < 10; ++i) {
        size_t tb = (size_t)(4 + ktS + i) * 256 + lane;
        wA[4 * i + 0] = Wb[tb];
        wA[4 * i + 1] = Wb[tb + 64];
        wA[4 * i + 2] = Wb[tb + 128];
        wA[4 * i + 3] = Wb[tb + 192];
    }
    const bool hasIt10 = (ktS + 10 < 76);
    const size_t tb10 = (size_t)(4 + ktS + 10) * 256 + lane;
    __syncthreads();
    // wave-0 loop-invariant bias vector for ai MFMA C-init
    v4f b2v;
    #pragma unroll
    for (int r = 0; r < 4; ++r) b2v[r] = b2_l[quad * 4 + r];

    int head = 0;
    #pragma unroll 1
    for (int t = 0; t < S_LEN; ++t) {
        head = (head == 0) ? (MEM - 1) : (head - 1);
        const int par = t & 1, np = par ^ 1;
        float v0, v1, v2, v3;

        // ---- Section 1: phase A via MFMA (wave = cell wv) ----
        {
            v8h bfrag = *(const v8h*)&ehH[bb4][quad * 8];
            v4f z4 = {0.f, 0.f, 0.f, 0.f};
            v4f zi = mfma16(aI, bfrag, z4);
            v4f zf = mfma16(aF, bfrag, z4);
            v4f zg = mfma16(aG, bfrag, z4);
            v4f zo = mfma16(aO, bfrag, z4);
            if (nn < 4) {
                int b = nn, c = wv;
                v4f hv4, cv4; v4h hr;
                #pragma unroll
                for (int r = 0; r < 4; ++r) {
                    int h = quad * 4 + r;
                    float cc = ecS[b][h];
                    float c2 = sigm(zf[r]) * cc + sigm(zi[r]) * tanh_f(zg[r]);
                    float hv = sigm(zo[r]) * tanh_f(c2);
                    hv4[r] = hv; cv4[r] = c2; hr[r] = (_Float16)hv;
                }
                *(v4f*)&nhS[c][b][quad * 4] = hv4;
                *(v4f*)&ncS[c][b][quad * 4] = cv4;
                *(v4h*)&RING(b, head, c * 16 + quad * 4) = hr;
            }
            if (tid < NB) errS[tid][head] = xS[tid][t] - predS[tid];
        }
        __syncthreads();   // B1

        // ---- Section 2a: m=0 MFMA (register A-frags) + parallel tail-prep ----
        {
            v8h bfrag = *(const v8h*)&RING(bb4, head, kcW * 32 + quad * 8);
            v4f z = {0.f, 0.f, 0.f, 0.f};
            v4f c0 = mfma16(m0A, bfrag, z);
            v4f c1 = mfma16(m0B, bfrag, z);
            if (nn < 4) {
                *(v4f*)&red0[kcW][nn][jt0W * 16 + quad * 4] = c0;
                *(v4f*)&red0[kcW][nn][(jt0W + 1) * 16 + quad * 4] = c1;
            }
            if (wv == 0) {
                E1P(0, v0) E1P(1, v1) E1P(2, v2) E1P(3, v3)
            } else if (wv == 1) {
                if (lane < 32) {
                    int bb = lane >> 3, c = lane & 7;
                    const float4* np_ = (const float4*)&nhS[c][bb][0];
                    const float4* wp = (const float4*)&Wo_l[c][0];
                    float s = bo_l[c];
                    #pragma unroll
                    for (int q4 = 0; q4 < 4; ++q4) s += dot4(np_[q4], wp[q4]);
                    oS[bb][c] = s;
                }
            } else if (wv == 2) {
                if (lane < NB) {
                    float th = 0.f;
                    #pragma unroll
                    for (int m = 0; m < 10; ++m) {
                        int sl = head + m; if (sl >= MEM) sl -= MEM;
                        th += fabsf(errS[lane][sl]);
                    }
                    th *= 0.25f;
                    thS[lane] = fminf(fmaxf(th, 0.f), 1.f);
                }
            } else if (wv >= 3 && wv < 7) {
                int bb = wv - 3;
                float s = 0.f;
                int sl = head;
                #pragma unroll
                for (int m = 0; m < MEM; ++m) {
                    s = fmaf(Werr_l[m * 64 + lane], errS[bb][sl], s);
                    ++sl; if (sl >= MEM) sl = 0;
                }
                errdotS[bb][lane] = s;
            }
        }
        __syncthreads();   // B2

        // ---- Section 2b: stream m=1..19 (waves 1-7, reg A-frags) || MFMA tail (wave 0) ----
        if (wv >= 1) {
            // prefetch iteration-10 frags (use is ~40 MFMAs away -> L2 latency hidden)
            v8h pA0, pA1, pA2, pA3;
            if (hasIt10) {
                pA0 = Wb[tb10]; pA1 = Wb[tb10 + 64];
                pA2 = Wb[tb10 + 128]; pA3 = Wb[tb10 + 192];
            }
            v4f c0 = {0.f,0.f,0.f,0.f}, c1 = {0.f,0.f,0.f,0.f};
            v4f c2 = {0.f,0.f,0.f,0.f}, c3 = {0.f,0.f,0.f,0.f};
            // iterations 0..9: register-resident A-frags
            #pragma unroll
            for (int i = 0; i < 10; ++i) {
                const int kt = ktS + i;
                const int mm = 1 + (kt >> 2), kc = kt & 3;
                int sl = head + mm - 1; if (sl >= MEM) sl -= MEM;
                v8h B = *(const v8h*)&RING(bb4, sl, kc * 32 + quad * 8);
                c0 = mfma16(wA[4 * i + 0], B, c0);
                c1 = mfma16(wA[4 * i + 1], B, c1);
                c2 = mfma16(wA[4 * i + 2], B, c2);
                c3 = mfma16(wA[4 * i + 3], B, c3);
            }
            // iteration 10 (prefetched; invalid only for wave 7)
            if (hasIt10) {
                const int kt = ktS + 10;
                const int mm = 1 + (kt >> 2), kc = kt & 3;
                int sl = head + mm - 1; if (sl >= MEM) sl -= MEM;
                v8h B = *(const v8h*)&RING(bb4, sl, kc * 32 + quad * 8);
                c0 = mfma16(pA0, B, c0);
                c1 = mfma16(pA1, B, c1);
                c2 = mfma16(pA2, B, c2);
                c3 = mfma16(pA3, B, c3);
            }
            if (nn < 4) {
                *(v4f*)&red[np][wv][nn][ 0 + quad * 4] = c0;
                *(v4f*)&red[np][wv][nn][16 + quad * 4] = c1;
                *(v4f*)&red[np][wv][nn][32 + quad * 4] = c2;
                *(v4f*)&red[np][wv][nn][48 + quad * 4] = c3;
            }
        } else {
            // ---- wave-0 MFMA tail ----
            // E1F -> e1B f16
            {
                float r0 = fmaxf(v0 + errdotS[0][lane]
                       + red0[0][0][lane] + red0[1][0][lane] + red0[2][0][lane] + red0[3][0][lane], 0.f);
                float r1 = fmaxf(v1 + errdotS[1][lane]
                       + red0[0][1][lane] + red0[1][1][lane] + red0[2][1][lane] + red0[3][1][lane], 0.f);
                float r2 = fmaxf(v2 + errdotS[2][lane]
                       + red0[0][2][lane] + red0[1][2][lane] + red0[2][2][lane] + red0[3][2][lane], 0.f);
                float r3 = fmaxf(v3 + errdotS[3][lane]
                       + red0[0][3][lane] + red0[1][3][lane] + red0[2][3][lane] + red0[3][3][lane], 0.f);
                e1B[0][lane] = (_Float16)r0;
                e1B[1][lane] = (_Float16)r1;
                e1B[2][lane] = (_Float16)r2;
                e1B[3][lane] = (_Float16)r3;
            }
            // ai = relu(W2 . e1 + b2): 2 chained MFMA, write agB0 inp slots
            {
                v8h bk0 = *(const v8h*)&e1B[bb4][quad * 8];
                v8h bk1 = *(const v8h*)&e1B[bb4][32 + quad * 8];
                v4f cai = mfma16(W2Fv[lane], bk0, b2v);
                cai = mfma16(W2Fv[64 + lane], bk1, cai);
                if (nn < 4) {
                    v4h av;
                    #pragma unroll
                    for (int r = 0; r < 4; ++r) av[r] = (_Float16)fmaxf(cai[r], 0.f);
                    *(v4h*)&agB0[nn][quad * 4] = av;
                }
            }
            // agent layer 0: 4 MFMA; activations on lanes nn<4
            {
                v8h bf = *(const v8h*)&agB0[bb4][quad * 8];
                v4f z4 = {0.f, 0.f, 0.f, 0.f};
                v4f zi = mfma16(WaGv[0 * 64 + lane], bf, z4);
                v4f zf = mfma16(WaGv[1 * 64 + lane], bf, z4);
                v4f zg = mfma16(WaGv[2 * 64 + lane], bf, z4);
                v4f zo = mfma16(WaGv[3 * 64 + lane], bf, z4);
                if (nn < 4) {
                    v4h hr;
                    #pragma unroll
                    for (int r = 0; r < 4; ++r) {
                        int g = quad * 4 + r;
                        float zi_ = zi[r] + ba_l[0][g], zf_ = zf[r] + ba_l[0][16 + g];
                        float zg_ = zg[r] + ba_l[0][32 + g], zo_ = zo[r] + ba_l[0][48 + g];
                        float c2 = sigm(zf_) * acS[0][nn][g] + sigm(zi_) * tanh_f(zg_);
                        acS[0][nn][g] = c2;
                        hr[r] = (_Float16)(sigm(zo_) * tanh_f(c2));
                    }
                    *(v4h*)&agB1[nn][quad * 4] = hr;       // layer-1 input (this step)
                    *(v4h*)&agB0[nn][16 + quad * 4] = hr;  // layer-0 hidden (next step)
                }
            }
            // agent layer 1: 4 MFMA; activations + ah1S f32
            {
                v8h bf = *(const v8h*)&agB1[bb4][quad * 8];
                v4f z4 = {0.f, 0.f, 0.f, 0.f};
                v4f zi = mfma16(WaGv[4 * 64 + lane], bf, z4);
                v4f zf = mfma16(WaGv[5 * 64 + lane], bf, z4);
                v4f zg = mfma16(WaGv[6 * 64 + lane], bf, z4);
                v4f zo = mfma16(WaGv[7 * 64 + lane], bf, z4);
                if (nn < 4) {
                    v4h hr; v4f hf;
                    #pragma unroll
                    for (int r = 0; r < 4; ++r) {
                        int g = quad * 4 + r;
                        float zi_ = zi[r] + ba_l[1][g], zf_ = zf[r] + ba_l[1][16 + g];
                        float zg_ = zg[r] + ba_l[1][32 + g], zo_ = zo[r] + ba_l[1][48 + g];
                        float c2 = sigm(zf_) * acS[1][nn][g] + sigm(zi_) * tanh_f(zg_);
                        acS[1][nn][g] = c2;
                        float hv = sigm(zo_) * tanh_f(c2);
                        hf[r] = hv; hr[r] = (_Float16)hv;
                    }
                    *(v4f*)&ah1S[nn][quad * 4] = hf;
                    *(v4h*)&agB1[nn][16 + quad * 4] = hr;  // layer-1 hidden (next step)
                }
            }
            const int j = lane;
            // gate logits + softmax + theta blend (lanes 0-31)
            if (j < 32) {
                int bb = j >> 3, c = j & 7;
                const float4* hp = (const float4*)&ah1S[bb][0];
                const float4* wg = (const float4*)&Wg_l[c][0];
                float s = bg_l[c];
                #pragma unroll
                for (int q = 0; q < 4; ++q) s += dot4(wg[q], hp[q]);
                glog[bb][c] = s;
                float4 ga = *(const float4*)&glog[bb][0];
                float4 gb = *(const float4*)&glog[bb][4];
                float mx = fmaxf(fmaxf(fmaxf(ga.x, ga.y), fmaxf(ga.z, ga.w)),
                                 fmaxf(fmaxf(gb.x, gb.y), fmaxf(gb.z, gb.w)));
                float sum = __expf(ga.x - mx) + __expf(ga.y - mx) + __expf(ga.z - mx) + __expf(ga.w - mx)
                          + __expf(gb.x - mx) + __expf(gb.y - mx) + __expf(gb.z - mx) + __expf(gb.w - mx);
                float p = __expf(s - mx) / sum;
                float th = thS[bb];
                gateS[bb][c] = p * th + gateS[bb][c] * (1.f - th);
            }
            // combine -> ehH + ecS
            {
                int bb = j >> 4, h = j & 15;
                float se = 0.f, sc = 0.f;
                #pragma unroll
                for (int c = 0; c < 8; ++c) {
                    float g = gateS[bb][c];
                    se = fmaf(g, nhS[c][bb][h], se);
                    sc = fmaf(g, ncS[c][bb][h], sc);
                }
                ehH[bb][h] = (_Float16)se;
                ecS[bb][h] = sc;
            }
            // pred + output + next x slot
            if (j < NB) {
                float s = 0.f;
                #pragma unroll
                for (int c = 0; c < 8; ++c) s = fmaf(gateS[j][c], oS[j][c], s);
                predS[j] = s;
                out[(b0 + j) * S_LEN + t] = s;
                ehH[j][16] = (_Float16)((t + 1 < S_LEN) ? xS[j][t + 1] : 0.f);
            }
        }
        __syncthreads();   // B3
    }
}

extern "C" void kernel_launch(void* const* d_in, const int* in_sizes, int n_in,
                              void* d_out, int out_size, void* d_ws, size_t ws_size,
                              hipStream_t stream) {
    const float* xp    = (const float*)d_in[0];
    const float* pred0 = (const float*)d_in[1];
    const float* gate0 = (const float*)d_in[2];
    const float* W_ih  = (const float*)d_in[3];
    const float* W_hh  = (const float*)d_in[4];
    const float* b_ih  = (const float*)d_in[5];
    const float* b_hh  = (const float*)d_in[6];
    const float* W_o   = (const float*)d_in[7];
    const float* b_o   = (const float*)d_in[8];
    const float* W1    = (const float*)d_in[9];
    const float* b1    = (const float*)d_in[10];
    const float* W2    = (const float*)d_in[11];
    const float* b2    = (const float*)d_in[12];
    const float* Wg    = (const float*)d_in[13];
    const float* bg    = (const float*)d_in[14];
    const float* Wa_ih = (const float*)d_in[15];
    const float* Wa_hh = (const float*)d_in[16];
    const float* ba_ih = (const float*)d_in[17];
    const float* ba_hh = (const float*)d_in[18];
    _Float16* W1F  = (_Float16*)d_ws;                // 163840 f16
    _Float16* WAF  = W1F + 163840;                   // 16384
    _Float16* W2F  = WAF + 16384;                    // 1024
    _Float16* WAGF = W2F + 1024;                     // 4096

    prep_w<<<(163840 + 16384 + 1024 + 4096 + 255) / 256, 256, 0, stream>>>(
        W1, W_hh, W_ih, b_ih, b_hh, W2, Wa_ih, Wa_hh, W1F, WAF, W2F, WAGF);
    mmoe_kernel<<<512 / NB, NTHR, 0, stream>>>(
        xp, pred0, gate0, W_ih, W_hh, b_ih, b_hh, W_o, b_o,
        W1, b1, W2, b2, Wg, bg, Wa_ih, Wa_hh, ba_ih, ba_hh,
        W1F, WAF, W2F, WAGF, (float*)d_out);
}

// Round 3
// 1297.824 us; speedup vs baseline: 1.2482x; 1.2482x over previous
//
#include <hip/hip_runtime.h>
#include <math.h>

#define S_LEN 256
#define NCELL 8
#define HID 16
#define MEM 20
#define NB 4
#define NTHR 512
#define RSTR 2592   // ring batch stride in f16 (bank skew)
#define RP 80       // reduction row stride (floats): bank shift 16 -> 2-way

typedef _Float16 v8h __attribute__((ext_vector_type(8)));
typedef _Float16 v4h __attribute__((ext_vector_type(4)));
typedef float v4f __attribute__((ext_vector_type(4)));

__device__ __forceinline__ float sigm(float v) { return 1.0f / (1.0f + __expf(-v)); }
__device__ __forceinline__ float tanh_f(float v) { return 1.0f - 2.0f / (__expf(2.0f * v) + 1.0f); }
__device__ __forceinline__ float dot4(float4 a, float4 b) {
    return fmaf(a.x, b.x, fmaf(a.y, b.y, fmaf(a.z, b.z, a.w * b.w)));
}
__device__ __forceinline__ v4f mfma16(v8h a, v8h b, v4f c) {
    return __builtin_amdgcn_mfma_f32_16x16x32_f16(a, b, c, 0, 0, 0);
}

#define RING(b, s, k) ringH[(b) * RSTR + (s) * 128 + (k)]

// prep: W1F (163840 f16, A-frag order, verified R11) + WAF (16384, expert
// cells) + W2F (1024, W2 as 2 K-tiles) + WAGF (4096, agent [Wa_ih|Wa_hh]
// K=32 A-frags, 2 layers x 4 gate-tiles).
__global__ __launch_bounds__(256)
void prep_w(const float* __restrict__ W1, const float* __restrict__ W_hh,
            const float* __restrict__ W_ih, const float* __restrict__ b_ih,
            const float* __restrict__ b_hh, const float* __restrict__ W2,
            const float* __restrict__ Wa_ih, const float* __restrict__ Wa_hh,
            _Float16* __restrict__ W1F, _Float16* __restrict__ WAF,
            _Float16* __restrict__ W2F, _Float16* __restrict__ WAGF) {
    int idx = blockIdx.x * 256 + threadIdx.x;
    if (idx < 163840) {
        int e = idx & 7, lane = (idx >> 3) & 63, jt = (idx >> 9) & 3, t = idx >> 11;
        int m = t >> 2, kc = t & 3;
        int j = jt * 16 + (lane & 15);
        int k = kc * 32 + (lane >> 4) * 8 + e;
        W1F[idx] = (_Float16)W1[j * 2580 + m * 129 + k];
    } else if (idx < 163840 + 16384) {
        int d = idx - 163840;
        int e = d & 7, lane = (d >> 3) & 63, gate = (d >> 9) & 3, c = d >> 11;
        int m = lane & 15, k = (lane >> 4) * 8 + e;
        int row = c * 64 + gate * 16 + m;
        float v = 0.f;
        if (k < 16) v = W_hh[row * 16 + k];
        else if (k == 16) v = W_ih[row];
        else if (k == 17) v = b_ih[row] + b_hh[row];
        WAF[d] = (_Float16)v;
    } else if (idx < 163840 + 16384 + 1024) {
        int d = idx - 163840 - 16384;
        int e = d & 7, lane = (d >> 3) & 63, kc = d >> 9;
        int i = lane & 15, k = kc * 32 + (lane >> 4) * 8 + e;
        W2F[d] = (_Float16)W2[i * 64 + k];
    } else if (idx < 163840 + 16384 + 1024 + 4096) {
        int d = idx - 163840 - 16384 - 1024;
        int e = d & 7, lane = (d >> 3) & 63, jt = (d >> 9) & 3, l = d >> 11;
        int g = jt * 16 + (lane & 15);
        int k = (lane >> 4) * 8 + e;
        float v = (k < 16) ? Wa_ih[(l * 64 + g) * 16 + k]
                           : Wa_hh[(l * 64 + g) * 16 + (k - 16)];
        WAGF[d] = (_Float16)v;
    }
}

// R20: R18/R19 (full register residency of W1F) both regressed: compiler
// pinned VGPR at 128 regardless of waves_per_eu, spilled/sank the frag
// array (WRITE_SIZE 0.5->21 MB). Abandoned. This round = exact R0 baseline
// (1268us, VGPR 80) + depth-3 rolling A-prefetch inside the 128-VGPR
// envelope: slots for iters i..i+2 in flight (48 VGPR), prologue issued at
// top-of-step so S1+S2a (~1000cy) covers the first L2 round trip; steady
// state gap issue->use = 3 iters. No allocator fight: loads are explicit,
// in-loop, rolling.
#define E1P(BB, V) { \
    V = b1_l[lane] \
      + red[par][1][BB][lane] + red[par][2][BB][lane] + red[par][3][BB][lane] \
      + red[par][4][BB][lane] + red[par][5][BB][lane] + red[par][6][BB][lane] \
      + red[par][7][BB][lane]; }

__global__ __attribute__((amdgpu_flat_work_group_size(NTHR, NTHR)))
void mmoe_kernel(const float* __restrict__ x, const float* __restrict__ pred0,
                 const float* __restrict__ gate0,
                 const float* __restrict__ W_ih, const float* __restrict__ W_hh,
                 const float* __restrict__ b_ih, const float* __restrict__ b_hh,
                 const float* __restrict__ W_o, const float* __restrict__ b_o,
                 const float* __restrict__ W1, const float* __restrict__ b1,
                 const float* __restrict__ W2, const float* __restrict__ b2,
                 const float* __restrict__ Wg, const float* __restrict__ bg,
                 const float* __restrict__ Wa_ih, const float* __restrict__ Wa_hh,
                 const float* __restrict__ ba_ih, const float* __restrict__ ba_hh,
                 const _Float16* __restrict__ W1F, const _Float16* __restrict__ WAF,
                 const _Float16* __restrict__ W2F, const _Float16* __restrict__ WAGF,
                 float* __restrict__ out)
{
    __shared__ __align__(16) _Float16 ringH[NB * RSTR];      // skewed ring (h rows)
    __shared__ __align__(16) _Float16 ehH[NB][40];           // [eh(16)|x|1|0..] f16
    __shared__ __align__(16) _Float16 W2F_l[2 * 512];        // ai A-frags
    __shared__ __align__(16) _Float16 WaG_l[2 * 4 * 512];    // agent A-frags
    __shared__ __align__(16) _Float16 e1B[NB][64];           // e1 f16 (ai B operand)
    __shared__ __align__(16) _Float16 agB0[NB][32];          // [inp|ah0] layer-0 B
    __shared__ __align__(16) _Float16 agB1[NB][32];          // [ah0|ah1] layer-1 B
    __shared__ float errS[NB][MEM];
    __shared__ float ba_l[2][64];
    __shared__ float b2_l[16];
    __shared__ __align__(16) float Wg_l[8][16], Wo_l[8][16];
    __shared__ float bg_l[8], bo_l[8];
    __shared__ float Werr_l[MEM * 64];
    __shared__ float b1_l[64];
    __shared__ float xS[NB][S_LEN];
    __shared__ __align__(16) float ecS[NB][HID];
    __shared__ __align__(16) float nhS[NCELL][NB][HID];      // [c][b][h]: 2-way banks
    __shared__ __align__(16) float ncS[NCELL][NB][HID];
    __shared__ float oS[NB][NCELL], predS[NB], gateS[NB][NCELL];
    __shared__ __align__(16) float acS[2][NB][HID];
    __shared__ __align__(16) float ah1S[NB][HID];            // layer-1 h, f32 (gate dot)
    __shared__ __align__(16) float glog[NB][8];
    __shared__ __align__(16) float red[2][8][NB][RP];        // stream partials (pad 80)
    __shared__ __align__(16) float red0[4][NB][RP];          // m=0 term (pad 80)
    __shared__ float errdotS[NB][64];
    __shared__ float thS[NB];

    const int tid = threadIdx.x;
    const int b0 = blockIdx.x * NB;
    const int lane = tid & 63, wv = tid >> 6;
    const int quad = lane >> 4, nn = lane & 15, bb4 = nn & 3;

    // ---- one-time staging ----
    for (int i = tid; i < 128; i += NTHR) { int l = i >> 6, g = i & 63; ba_l[l][g] = ba_ih[i] + ba_hh[i]; }
    for (int i = tid; i < 1024; i += NTHR) W2F_l[i] = W2F[i];
    for (int i = tid; i < 4096; i += NTHR) WaG_l[i] = WAGF[i];
    for (int i = tid; i < 1280; i += NTHR) { int m = i >> 6, j = i & 63; Werr_l[i] = W1[j * 2580 + m * 129 + 128]; }
    if (tid < 64) b1_l[tid] = b1[tid];
    if (tid < 16) b2_l[tid] = b2[tid];
    if (tid < 128) { int c = tid >> 4, h = tid & 15; Wg_l[c][h] = Wg[tid]; Wo_l[c][h] = W_o[tid]; }
    if (tid < 8) { bg_l[tid] = bg[tid]; bo_l[tid] = b_o[tid]; }
    for (int i = tid; i < NB * S_LEN; i += NTHR) { int b = i >> 8, s = i & 255; xS[b][s] = x[(b0 + b) * S_LEN + s]; }
    for (int i = tid; i < NB * RSTR; i += NTHR) ringH[i] = (_Float16)0.0f;
    for (int i = tid; i < 2 * 8 * NB * RP; i += NTHR) ((float*)red)[i] = 0.0f;
    for (int i = tid; i < NB * 32; i += NTHR) { ((_Float16*)agB0)[i] = (_Float16)0.0f; ((_Float16*)agB1)[i] = (_Float16)0.0f; }
    if (tid < NB * 40) {
        int n = tid / 40, k = tid % 40;
        float v = 0.f;
        if (k == 16) v = x[(b0 + n) * S_LEN + 0];
        else if (k == 17) v = 1.0f;
        ehH[n][k] = (_Float16)v;
    }
    if (tid < NB * MEM) { int b = tid / MEM, m = tid % MEM; errS[b][m] = 0.5f; }
    if (tid < NB * HID) {
        int b = tid >> 4, h = tid & 15;
        ecS[b][h] = 0.f;
        acS[0][b][h] = 0.f; acS[1][b][h] = 0.f;
        ah1S[b][h] = 0.f;
    }
    if (tid < NB) predS[tid] = pred0[b0 + tid];
    if (tid < NB * NCELL) { int b = tid >> 3, c = tid & 7; gateS[b][c] = gate0[(b0 + b) * NCELL + c]; }

    // ---- loop-invariant register A-frags ----
    const v8h* WA = (const v8h*)WAF;
    v8h aI = WA[(wv * 4 + 0) * 64 + lane];
    v8h aF = WA[(wv * 4 + 1) * 64 + lane];
    v8h aG = WA[(wv * 4 + 2) * 64 + lane];
    v8h aO = WA[(wv * 4 + 3) * 64 + lane];
    const v8h* Wb = (const v8h*)W1F;
    const int kcW = wv >> 1, jt0W = (wv & 1) * 2;
    v8h m0A = Wb[(size_t)(kcW * 4 + jt0W) * 64 + lane];
    v8h m0B = Wb[(size_t)(kcW * 4 + jt0W + 1) * 64 + lane];
    const v8h* W2Fv = (const v8h*)W2F_l;
    const v8h* WaGv = (const v8h*)WaG_l;
    const int ktS = (wv >= 1) ? (wv - 1) * 11 : 0;
    __syncthreads();
    // wave-0 loop-invariant bias vector for ai MFMA C-init
    v4f b2v;
    #pragma unroll
    for (int r = 0; r < 4; ++r) b2v[r] = b2_l[quad * 4 + r];

    int head = 0;
    #pragma unroll 1
    for (int t = 0; t < S_LEN; ++t) {
        head = (head == 0) ? (MEM - 1) : (head - 1);
        const int par = t & 1, np = par ^ 1;
        float v0, v1, v2, v3;

        // ---- R20: depth-3 rolling A-frag slots; prologue issued here so
        // S1+S2a (~1000cy) hides the first L2 round trip. Addresses are
        // step-invariant (W1F is constant).
        v8h sA0[3], sA1[3], sA2[3], sA3[3];
        if (wv >= 1) {
            #pragma unroll
            for (int i = 0; i < 3; ++i) {
                int kt = ktS + i; if (kt > 75) kt = 75;
                size_t tb = (size_t)(4 + kt) * 256 + lane;
                sA0[i] = Wb[tb];       sA1[i] = Wb[tb + 64];
                sA2[i] = Wb[tb + 128]; sA3[i] = Wb[tb + 192];
            }
        }

        // ---- Section 1: phase A via MFMA (wave = cell wv) ----
        {
            v8h bfrag = *(const v8h*)&ehH[bb4][quad * 8];
            v4f z4 = {0.f, 0.f, 0.f, 0.f};
            v4f zi = mfma16(aI, bfrag, z4);
            v4f zf = mfma16(aF, bfrag, z4);
            v4f zg = mfma16(aG, bfrag, z4);
            v4f zo = mfma16(aO, bfrag, z4);
            if (nn < 4) {
                int b = nn, c = wv;
                v4f hv4, cv4; v4h hr;
                #pragma unroll
                for (int r = 0; r < 4; ++r) {
                    int h = quad * 4 + r;
                    float cc = ecS[b][h];
                    float c2 = sigm(zf[r]) * cc + sigm(zi[r]) * tanh_f(zg[r]);
                    float hv = sigm(zo[r]) * tanh_f(c2);
                    hv4[r] = hv; cv4[r] = c2; hr[r] = (_Float16)hv;
                }
                *(v4f*)&nhS[c][b][quad * 4] = hv4;
                *(v4f*)&ncS[c][b][quad * 4] = cv4;
                *(v4h*)&RING(b, head, c * 16 + quad * 4) = hr;
            }
            if (tid < NB) errS[tid][head] = xS[tid][t] - predS[tid];
        }
        __syncthreads();   // B1

        // ---- Section 2a: m=0 MFMA (register A-frags) + parallel tail-prep ----
        {
            v8h bfrag = *(const v8h*)&RING(bb4, head, kcW * 32 + quad * 8);
            v4f z = {0.f, 0.f, 0.f, 0.f};
            v4f c0 = mfma16(m0A, bfrag, z);
            v4f c1 = mfma16(m0B, bfrag, z);
            if (nn < 4) {
                *(v4f*)&red0[kcW][nn][jt0W * 16 + quad * 4] = c0;
                *(v4f*)&red0[kcW][nn][(jt0W + 1) * 16 + quad * 4] = c1;
            }
            if (wv == 0) {
                E1P(0, v0) E1P(1, v1) E1P(2, v2) E1P(3, v3)
            } else if (wv == 1) {
                if (lane < 32) {
                    int bb = lane >> 3, c = lane & 7;
                    const float4* np_ = (const float4*)&nhS[c][bb][0];
                    const float4* wp = (const float4*)&Wo_l[c][0];
                    float s = bo_l[c];
                    #pragma unroll
                    for (int q4 = 0; q4 < 4; ++q4) s += dot4(np_[q4], wp[q4]);
                    oS[bb][c] = s;
                }
            } else if (wv == 2) {
                if (lane < NB) {
                    float th = 0.f;
                    #pragma unroll
                    for (int m = 0; m < 10; ++m) {
                        int sl = head + m; if (sl >= MEM) sl -= MEM;
                        th += fabsf(errS[lane][sl]);
                    }
                    th *= 0.25f;
                    thS[lane] = fminf(fmaxf(th, 0.f), 1.f);
                }
            } else if (wv >= 3 && wv < 7) {
                int bb = wv - 3;
                float s = 0.f;
                int sl = head;
                #pragma unroll
                for (int m = 0; m < MEM; ++m) {
                    s = fmaf(Werr_l[m * 64 + lane], errS[bb][sl], s);
                    ++sl; if (sl >= MEM) sl = 0;
                }
                errdotS[bb][lane] = s;
            }
        }
        __syncthreads();   // B2

        // ---- Section 2b: stream m=1..19 (waves 1-7, rolling depth-3) || MFMA tail (wave 0) ----
        if (wv >= 1) {
            v4f c0 = {0.f,0.f,0.f,0.f}, c1 = {0.f,0.f,0.f,0.f};
            v4f c2 = {0.f,0.f,0.f,0.f}, c3 = {0.f,0.f,0.f,0.f};
            #pragma unroll
            for (int i = 0; i < 11; ++i) {
                const int s3 = i % 3;
                const int kt = ktS + i;
                if (kt < 76) {                      // uniform; false only wv=7,i=10
                    const int mm = 1 + (kt >> 2), kc = kt & 3;
                    int sl = head + mm - 1; if (sl >= MEM) sl -= MEM;
                    v8h B = *(const v8h*)&RING(bb4, sl, kc * 32 + quad * 8);
                    c0 = mfma16(sA0[s3], B, c0);
                    c1 = mfma16(sA1[s3], B, c1);
                    c2 = mfma16(sA2[s3], B, c2);
                    c3 = mfma16(sA3[s3], B, c3);
                }
                if (i + 3 < 11) {                   // refill slot for iter i+3
                    int ktn = ktS + i + 3; if (ktn > 75) ktn = 75;
                    size_t tb = (size_t)(4 + ktn) * 256 + lane;
                    sA0[s3] = Wb[tb];       sA1[s3] = Wb[tb + 64];
                    sA2[s3] = Wb[tb + 128]; sA3[s3] = Wb[tb + 192];
                }
            }
            if (nn < 4) {
                *(v4f*)&red[np][wv][nn][ 0 + quad * 4] = c0;
                *(v4f*)&red[np][wv][nn][16 + quad * 4] = c1;
                *(v4f*)&red[np][wv][nn][32 + quad * 4] = c2;
                *(v4f*)&red[np][wv][nn][48 + quad * 4] = c3;
            }
        } else {
            // ---- wave-0 MFMA tail ----
            // E1F -> e1B f16
            {
                float r0 = fmaxf(v0 + errdotS[0][lane]
                       + red0[0][0][lane] + red0[1][0][lane] + red0[2][0][lane] + red0[3][0][lane], 0.f);
                float r1 = fmaxf(v1 + errdotS[1][lane]
                       + red0[0][1][lane] + red0[1][1][lane] + red0[2][1][lane] + red0[3][1][lane], 0.f);
                float r2 = fmaxf(v2 + errdotS[2][lane]
                       + red0[0][2][lane] + red0[1][2][lane] + red0[2][2][lane] + red0[3][2][lane], 0.f);
                float r3 = fmaxf(v3 + errdotS[3][lane]
                       + red0[0][3][lane] + red0[1][3][lane] + red0[2][3][lane] + red0[3][3][lane], 0.f);
                e1B[0][lane] = (_Float16)r0;
                e1B[1][lane] = (_Float16)r1;
                e1B[2][lane] = (_Float16)r2;
                e1B[3][lane] = (_Float16)r3;
            }
            // ai = relu(W2 . e1 + b2): 2 chained MFMA, write agB0 inp slots
            {
                v8h bk0 = *(const v8h*)&e1B[bb4][quad * 8];
                v8h bk1 = *(const v8h*)&e1B[bb4][32 + quad * 8];
                v4f cai = mfma16(W2Fv[lane], bk0, b2v);
                cai = mfma16(W2Fv[64 + lane], bk1, cai);
                if (nn < 4) {
                    v4h av;
                    #pragma unroll
                    for (int r = 0; r < 4; ++r) av[r] = (_Float16)fmaxf(cai[r], 0.f);
                    *(v4h*)&agB0[nn][quad * 4] = av;
                }
            }
            // agent layer 0: 4 MFMA; activations on lanes nn<4
            {
                v8h bf = *(const v8h*)&agB0[bb4][quad * 8];
                v4f z4 = {0.f, 0.f, 0.f, 0.f};
                v4f zi = mfma16(WaGv[0 * 64 + lane], bf, z4);
                v4f zf = mfma16(WaGv[1 * 64 + lane], bf, z4);
                v4f zg = mfma16(WaGv[2 * 64 + lane], bf, z4);
                v4f zo = mfma16(WaGv[3 * 64 + lane], bf, z4);
                if (nn < 4) {
                    v4h hr;
                    #pragma unroll
                    for (int r = 0; r < 4; ++r) {
                        int g = quad * 4 + r;
                        float zi_ = zi[r] + ba_l[0][g], zf_ = zf[r] + ba_l[0][16 + g];
                        float zg_ = zg[r] + ba_l[0][32 + g], zo_ = zo[r] + ba_l[0][48 + g];
                        float c2 = sigm(zf_) * acS[0][nn][g] + sigm(zi_) * tanh_f(zg_);
                        acS[0][nn][g] = c2;
                        hr[r] = (_Float16)(sigm(zo_) * tanh_f(c2));
                    }
                    *(v4h*)&agB1[nn][quad * 4] = hr;       // layer-1 input (this step)
                    *(v4h*)&agB0[nn][16 + quad * 4] = hr;  // layer-0 hidden (next step)
                }
            }
            // agent layer 1: 4 MFMA; activations + ah1S f32
            {
                v8h bf = *(const v8h*)&agB1[bb4][quad * 8];
                v4f z4 = {0.f, 0.f, 0.f, 0.f};
                v4f zi = mfma16(WaGv[4 * 64 + lane], bf, z4);
                v4f zf = mfma16(WaGv[5 * 64 + lane], bf, z4);
                v4f zg = mfma16(WaGv[6 * 64 + lane], bf, z4);
                v4f zo = mfma16(WaGv[7 * 64 + lane], bf, z4);
                if (nn < 4) {
                    v4h hr; v4f hf;
                    #pragma unroll
                    for (int r = 0; r < 4; ++r) {
                        int g = quad * 4 + r;
                        float zi_ = zi[r] + ba_l[1][g], zf_ = zf[r] + ba_l[1][16 + g];
                        float zg_ = zg[r] + ba_l[1][32 + g], zo_ = zo[r] + ba_l[1][48 + g];
                        float c2 = sigm(zf_) * acS[1][nn][g] + sigm(zi_) * tanh_f(zg_);
                        acS[1][nn][g] = c2;
                        float hv = sigm(zo_) * tanh_f(c2);
                        hf[r] = hv; hr[r] = (_Float16)hv;
                    }
                    *(v4f*)&ah1S[nn][quad * 4] = hf;
                    *(v4h*)&agB1[nn][16 + quad * 4] = hr;  // layer-1 hidden (next step)
                }
            }
            const int j = lane;
            // gate logits + softmax + theta blend (lanes 0-31)
            if (j < 32) {
                int bb = j >> 3, c = j & 7;
                const float4* hp = (const float4*)&ah1S[bb][0];
                const float4* wg = (const float4*)&Wg_l[c][0];
                float s = bg_l[c];
                #pragma unroll
                for (int q = 0; q < 4; ++q) s += dot4(wg[q], hp[q]);
                glog[bb][c] = s;
                float4 ga = *(const float4*)&glog[bb][0];
                float4 gb = *(const float4*)&glog[bb][4];
                float mx = fmaxf(fmaxf(fmaxf(ga.x, ga.y), fmaxf(ga.z, ga.w)),
                                 fmaxf(fmaxf(gb.x, gb.y), fmaxf(gb.z, gb.w)));
                float sum = __expf(ga.x - mx) + __expf(ga.y - mx) + __expf(ga.z - mx) + __expf(ga.w - mx)
                          + __expf(gb.x - mx) + __expf(gb.y - mx) + __expf(gb.z - mx) + __expf(gb.w - mx);
                float p = __expf(s - mx) / sum;
                float th = thS[bb];
                gateS[bb][c] = p * th + gateS[bb][c] * (1.f - th);
            }
            // combine -> ehH + ecS
            {
                int bb = j >> 4, h = j & 15;
                float se = 0.f, sc = 0.f;
                #pragma unroll
                for (int c = 0; c < 8; ++c) {
                    float g = gateS[bb][c];
                    se = fmaf(g, nhS[c][bb][h], se);
                    sc = fmaf(g, ncS[c][bb][h], sc);
                }
                ehH[bb][h] = (_Float16)se;
                ecS[bb][h] = sc;
            }
            // pred + output + next x slot
            if (j < NB) {
                float s = 0.f;
                #pragma unroll
                for (int c = 0; c < 8; ++c) s = fmaf(gateS[j][c], oS[j][c], s);
                predS[j] = s;
                out[(b0 + j) * S_LEN + t] = s;
                ehH[j][16] = (_Float16)((t + 1 < S_LEN) ? xS[j][t + 1] : 0.f);
            }
        }
        __syncthreads();   // B3
    }
}

extern "C" void kernel_launch(void* const* d_in, const int* in_sizes, int n_in,
                              void* d_out, int out_size, void* d_ws, size_t ws_size,
                              hipStream_t stream) {
    const float* xp    = (const float*)d_in[0];
    const float* pred0 = (const float*)d_in[1];
    const float* gate0 = (const float*)d_in[2];
    const float* W_ih  = (const float*)d_in[3];
    const float* W_hh  = (const float*)d_in[4];
    const float* b_ih  = (const float*)d_in[5];
    const float* b_hh  = (const float*)d_in[6];
    const float* W_o   = (const float*)d_in[7];
    const float* b_o   = (const float*)d_in[8];
    const float* W1    = (const float*)d_in[9];
    const float* b1    = (const float*)d_in[10];
    const float* W2    = (const float*)d_in[11];
    const float* b2    = (const float*)d_in[12];
    const float* Wg    = (const float*)d_in[13];
    const float* bg    = (const float*)d_in[14];
    const float* Wa_ih = (const float*)d_in[15];
    const float* Wa_hh = (const float*)d_in[16];
    const float* ba_ih = (const float*)d_in[17];
    const float* ba_hh = (const float*)d_in[18];
    _Float16* W1F  = (_Float16*)d_ws;                // 163840 f16
    _Float16* WAF  = W1F + 163840;                   // 16384
    _Float16* W2F  = WAF + 16384;                    // 1024
    _Float16* WAGF = W2F + 1024;                     // 4096

    prep_w<<<(163840 + 16384 + 1024 + 4096 + 255) / 256, 256, 0, stream>>>(
        W1, W_hh, W_ih, b_ih, b_hh, W2, Wa_ih, Wa_hh, W1F, WAF, W2F, WAGF);
    mmoe_kernel<<<512 / NB, NTHR, 0, stream>>>(
        xp, pred0, gate0, W_ih, W_hh, b_ih, b_hh, W_o, b_o,
        W1, b1, W2, b2, Wg, bg, Wa_ih, Wa_hh, ba_ih, ba_hh,
        W1F, WAF, W2F, WAGF, (float*)d_out);
}

// Round 4
// 1269.874 us; speedup vs baseline: 1.2757x; 1.0220x over previous
//
#include <hip/hip_runtime.h>
#include <math.h>

#define S_LEN 256
#define NCELL 8
#define HID 16
#define MEM 20
#define NB 4
#define NTHR 512
#define RSTR 2592   // ring batch stride in f16 (bank skew)
#define RP 80       // reduction row stride (floats): bank shift 16 -> 2-way

typedef _Float16 v8h __attribute__((ext_vector_type(8)));
typedef _Float16 v4h __attribute__((ext_vector_type(4)));
typedef float v4f __attribute__((ext_vector_type(4)));
typedef int v2i __attribute__((ext_vector_type(2)));
typedef int v4i __attribute__((ext_vector_type(4)));

__device__ __forceinline__ float sigm(float v) { return 1.0f / (1.0f + __expf(-v)); }
__device__ __forceinline__ float tanh_f(float v) { return 1.0f - 2.0f / (__expf(2.0f * v) + 1.0f); }
__device__ __forceinline__ float dot4(float4 a, float4 b) {
    return fmaf(a.x, b.x, fmaf(a.y, b.y, fmaf(a.z, b.z, a.w * b.w)));
}
__device__ __forceinline__ v4f mfma16(v8h a, v8h b, v4f c) {
    return __builtin_amdgcn_mfma_f32_16x16x32_f16(a, b, c, 0, 0, 0);
}
__device__ __forceinline__ int bperm(int idx4, int v) {
    return __builtin_amdgcn_ds_bpermute(idx4, v);
}

#define RING(b, s, k) ringH[(b) * RSTR + (s) * 128 + (k)]

// prep: W1F (163840 f16, A-frag order, verified R11) + WAF (16384, expert
// cells) + W2F (1024, W2 as 2 K-tiles) + WAGF (4096, agent [Wa_ih|Wa_hh]
// K=32 A-frags, 2 layers x 4 gate-tiles).
__global__ __launch_bounds__(256)
void prep_w(const float* __restrict__ W1, const float* __restrict__ W_hh,
            const float* __restrict__ W_ih, const float* __restrict__ b_ih,
            const float* __restrict__ b_hh, const float* __restrict__ W2,
            const float* __restrict__ Wa_ih, const float* __restrict__ Wa_hh,
            _Float16* __restrict__ W1F, _Float16* __restrict__ WAF,
            _Float16* __restrict__ W2F, _Float16* __restrict__ WAGF) {
    int idx = blockIdx.x * 256 + threadIdx.x;
    if (idx < 163840) {
        int e = idx & 7, lane = (idx >> 3) & 63, jt = (idx >> 9) & 3, t = idx >> 11;
        int m = t >> 2, kc = t & 3;
        int j = jt * 16 + (lane & 15);
        int k = kc * 32 + (lane >> 4) * 8 + e;
        W1F[idx] = (_Float16)W1[j * 2580 + m * 129 + k];
    } else if (idx < 163840 + 16384) {
        int d = idx - 163840;
        int e = d & 7, lane = (d >> 3) & 63, gate = (d >> 9) & 3, c = d >> 11;
        int m = lane & 15, k = (lane >> 4) * 8 + e;
        int row = c * 64 + gate * 16 + m;
        float v = 0.f;
        if (k < 16) v = W_hh[row * 16 + k];
        else if (k == 16) v = W_ih[row];
        else if (k == 17) v = b_ih[row] + b_hh[row];
        WAF[d] = (_Float16)v;
    } else if (idx < 163840 + 16384 + 1024) {
        int d = idx - 163840 - 16384;
        int e = d & 7, lane = (d >> 3) & 63, kc = d >> 9;
        int i = lane & 15, k = kc * 32 + (lane >> 4) * 8 + e;
        W2F[d] = (_Float16)W2[i * 64 + k];
    } else if (idx < 163840 + 16384 + 1024 + 4096) {
        int d = idx - 163840 - 16384 - 1024;
        int e = d & 7, lane = (d >> 3) & 63, jt = (d >> 9) & 3, l = d >> 11;
        int g = jt * 16 + (lane & 15);
        int k = (lane >> 4) * 8 + e;
        float v = (k < 16) ? Wa_ih[(l * 64 + g) * 16 + k]
                           : Wa_hh[(l * 64 + g) * 16 + (k - 16)];
        WAGF[d] = (_Float16)v;
    }
}

// R21: tail-chain surgery. R20 proved the stream is fully hidden (depth-3
// prefetch neutral, VALUBusy 29.6->20.7 at constant dur) -> wave-0 tail is
// the 2b span. Diet: replicated activations on all 64 lanes; agent state
// (ac, h-prev, gate) in wave-persistent registers; agB0/agB1/ah1S/glog/
// gateS/acS LDS eliminated (B-frags via ds_bpermute, gate softmax in-reg
// with shfl_xor reduce, combine pulls gates via bpermute); all static-addr
// operands early-issued. Cross-wave interfaces (e1B, nhS/ncS, red*, ehH,
// ecS, oS, thS, errdotS) unchanged. Stream = R0 depth-1 (proven).
#define E1P(BB, V) { \
    V = b1_l[lane] \
      + red[par][1][BB][lane] + red[par][2][BB][lane] + red[par][3][BB][lane] \
      + red[par][4][BB][lane] + red[par][5][BB][lane] + red[par][6][BB][lane] \
      + red[par][7][BB][lane]; }

__global__ __attribute__((amdgpu_flat_work_group_size(NTHR, NTHR)))
void mmoe_kernel(const float* __restrict__ x, const float* __restrict__ pred0,
                 const float* __restrict__ gate0,
                 const float* __restrict__ W_ih, const float* __restrict__ W_hh,
                 const float* __restrict__ b_ih, const float* __restrict__ b_hh,
                 const float* __restrict__ W_o, const float* __restrict__ b_o,
                 const float* __restrict__ W1, const float* __restrict__ b1,
                 const float* __restrict__ W2, const float* __restrict__ b2,
                 const float* __restrict__ Wg, const float* __restrict__ bg,
                 const float* __restrict__ Wa_ih, const float* __restrict__ Wa_hh,
                 const float* __restrict__ ba_ih, const float* __restrict__ ba_hh,
                 const _Float16* __restrict__ W1F, const _Float16* __restrict__ WAF,
                 const _Float16* __restrict__ W2F, const _Float16* __restrict__ WAGF,
                 float* __restrict__ out)
{
    __shared__ __align__(16) _Float16 ringH[NB * RSTR];      // skewed ring (h rows)
    __shared__ __align__(16) _Float16 ehH[NB][40];           // [eh(16)|x|1|0..] f16
    __shared__ __align__(16) _Float16 W2F_l[2 * 512];        // ai A-frags
    __shared__ __align__(16) _Float16 WaG_l[2 * 4 * 512];    // agent A-frags
    __shared__ __align__(16) _Float16 e1B[NB][64];           // e1 f16 (ai B operand)
    __shared__ float errS[NB][MEM];
    __shared__ __align__(16) float ba_l[2][64];
    __shared__ float b2_l[16];
    __shared__ __align__(16) float Wg_l[8][16], Wo_l[8][16];
    __shared__ float bg_l[8], bo_l[8];
    __shared__ float Werr_l[MEM * 64];
    __shared__ float b1_l[64];
    __shared__ float xS[NB][S_LEN];
    __shared__ __align__(16) float ecS[NB][HID];
    __shared__ __align__(16) float nhS[NCELL][NB][HID];      // [c][b][h]: 2-way banks
    __shared__ __align__(16) float ncS[NCELL][NB][HID];
    __shared__ __align__(16) float oS[NB][NCELL];
    __shared__ float predS[NB];
    __shared__ __align__(16) float red[2][8][NB][RP];        // stream partials (pad 80)
    __shared__ __align__(16) float red0[4][NB][RP];          // m=0 term (pad 80)
    __shared__ float errdotS[NB][64];
    __shared__ float thS[NB];

    const int tid = threadIdx.x;
    const int b0 = blockIdx.x * NB;
    const int lane = tid & 63, wv = tid >> 6;
    const int quad = lane >> 4, nn = lane & 15, bb4 = nn & 3;

    // ---- one-time staging ----
    for (int i = tid; i < 128; i += NTHR) { int l = i >> 6, g = i & 63; ba_l[l][g] = ba_ih[i] + ba_hh[i]; }
    for (int i = tid; i < 1024; i += NTHR) W2F_l[i] = W2F[i];
    for (int i = tid; i < 4096; i += NTHR) WaG_l[i] = WAGF[i];
    for (int i = tid; i < 1280; i += NTHR) { int m = i >> 6, j = i & 63; Werr_l[i] = W1[j * 2580 + m * 129 + 128]; }
    if (tid < 64) b1_l[tid] = b1[tid];
    if (tid < 16) b2_l[tid] = b2[tid];
    if (tid < 128) { int c = tid >> 4, h = tid & 15; Wg_l[c][h] = Wg[tid]; Wo_l[c][h] = W_o[tid]; }
    if (tid < 8) { bg_l[tid] = bg[tid]; bo_l[tid] = b_o[tid]; }
    for (int i = tid; i < NB * S_LEN; i += NTHR) { int b = i >> 8, s = i & 255; xS[b][s] = x[(b0 + b) * S_LEN + s]; }
    for (int i = tid; i < NB * RSTR; i += NTHR) ringH[i] = (_Float16)0.0f;
    for (int i = tid; i < 2 * 8 * NB * RP; i += NTHR) ((float*)red)[i] = 0.0f;
    if (tid < NB * 40) {
        int n = tid / 40, k = tid % 40;
        float v = 0.f;
        if (k == 16) v = x[(b0 + n) * S_LEN + 0];
        else if (k == 17) v = 1.0f;
        ehH[n][k] = (_Float16)v;
    }
    if (tid < NB * MEM) { int b = tid / MEM, m = tid % MEM; errS[b][m] = 0.5f; }
    if (tid < NB * HID) { int b = tid >> 4, h = tid & 15; ecS[b][h] = 0.f; }
    if (tid < NB) predS[tid] = pred0[b0 + tid];

    // ---- wave-persistent tail state (meaningful on wave 0; harmless elsewhere) ----
    float gS0 = gate0[(b0 + bb4) * NCELL + 0], gS1 = gate0[(b0 + bb4) * NCELL + 1];
    float gS2 = gate0[(b0 + bb4) * NCELL + 2], gS3 = gate0[(b0 + bb4) * NCELL + 3];
    float gS4 = gate0[(b0 + bb4) * NCELL + 4], gS5 = gate0[(b0 + bb4) * NCELL + 5];
    float gS6 = gate0[(b0 + bb4) * NCELL + 6], gS7 = gate0[(b0 + bb4) * NCELL + 7];
    v4f ac0 = {0.f, 0.f, 0.f, 0.f}, ac1 = {0.f, 0.f, 0.f, 0.f};
    v2i h0p = {0, 0}, h1p = {0, 0};

    // ---- loop-invariant register A-frags ----
    const v8h* WA = (const v8h*)WAF;
    v8h aI = WA[(wv * 4 + 0) * 64 + lane];
    v8h aF = WA[(wv * 4 + 1) * 64 + lane];
    v8h aG = WA[(wv * 4 + 2) * 64 + lane];
    v8h aO = WA[(wv * 4 + 3) * 64 + lane];
    const v8h* Wb = (const v8h*)W1F;
    const int kcW = wv >> 1, jt0W = (wv & 1) * 2;
    v8h m0A = Wb[(size_t)(kcW * 4 + jt0W) * 64 + lane];
    v8h m0B = Wb[(size_t)(kcW * 4 + jt0W + 1) * 64 + lane];
    const v8h* W2Fv = (const v8h*)W2F_l;
    const v8h* WaGv = (const v8h*)WaG_l;
    __syncthreads();
    // wave-0 loop-invariant bias vector for ai MFMA C-init
    v4f b2v;
    #pragma unroll
    for (int r = 0; r < 4; ++r) b2v[r] = b2_l[quad * 4 + r];

    int head = 0;
    #pragma unroll 1
    for (int t = 0; t < S_LEN; ++t) {
        head = (head == 0) ? (MEM - 1) : (head - 1);
        const int par = t & 1, np = par ^ 1;
        float v0, v1, v2, v3;

        // ---- Section 1: phase A via MFMA (wave = cell wv) ----
        {
            v4f ecv = *(const v4f*)&ecS[bb4][quad * 4];       // early issue
            v8h bfrag = *(const v8h*)&ehH[bb4][quad * 8];
            v4f z4 = {0.f, 0.f, 0.f, 0.f};
            v4f zi = mfma16(aI, bfrag, z4);
            v4f zf = mfma16(aF, bfrag, z4);
            v4f zg = mfma16(aG, bfrag, z4);
            v4f zo = mfma16(aO, bfrag, z4);
            // replicated activation on all 64 lanes (cols 4-15 = copies)
            v4f hv4, cv4; v4h hrS;
            #pragma unroll
            for (int r = 0; r < 4; ++r) {
                float c2 = sigm(zf[r]) * ecv[r] + sigm(zi[r]) * tanh_f(zg[r]);
                float hv = sigm(zo[r]) * tanh_f(c2);
                hv4[r] = hv; cv4[r] = c2; hrS[r] = (_Float16)hv;
            }
            if (nn < 4) {
                *(v4f*)&nhS[wv][nn][quad * 4] = hv4;
                *(v4f*)&ncS[wv][nn][quad * 4] = cv4;
                *(v4h*)&RING(nn, head, wv * 16 + quad * 4) = hrS;
            }
            if (tid < NB) errS[tid][head] = xS[tid][t] - predS[tid];
        }
        __syncthreads();   // B1

        // ---- Section 2a: m=0 MFMA (register A-frags) + parallel tail-prep ----
        {
            v8h bfrag = *(const v8h*)&RING(bb4, head, kcW * 32 + quad * 8);
            v4f z = {0.f, 0.f, 0.f, 0.f};
            v4f c0 = mfma16(m0A, bfrag, z);
            v4f c1 = mfma16(m0B, bfrag, z);
            if (nn < 4) {
                *(v4f*)&red0[kcW][nn][jt0W * 16 + quad * 4] = c0;
                *(v4f*)&red0[kcW][nn][(jt0W + 1) * 16 + quad * 4] = c1;
            }
            if (wv == 0) {
                E1P(0, v0) E1P(1, v1) E1P(2, v2) E1P(3, v3)
            } else if (wv == 1) {
                if (lane < 32) {
                    int bb = lane >> 3, c = lane & 7;
                    const float4* np_ = (const float4*)&nhS[c][bb][0];
                    const float4* wp = (const float4*)&Wo_l[c][0];
                    float s = bo_l[c];
                    #pragma unroll
                    for (int q4 = 0; q4 < 4; ++q4) s += dot4(np_[q4], wp[q4]);
                    oS[bb][c] = s;
                }
            } else if (wv == 2) {
                if (lane < NB) {
                    float th = 0.f;
                    #pragma unroll
                    for (int m = 0; m < 10; ++m) {
                        int sl = head + m; if (sl >= MEM) sl -= MEM;
                        th += fabsf(errS[lane][sl]);
                    }
                    th *= 0.25f;
                    thS[lane] = fminf(fmaxf(th, 0.f), 1.f);
                }
            } else if (wv >= 3 && wv < 7) {
                int bb = wv - 3;
                float s = 0.f;
                int sl = head;
                #pragma unroll
                for (int m = 0; m < MEM; ++m) {
                    s = fmaf(Werr_l[m * 64 + lane], errS[bb][sl], s);
                    ++sl; if (sl >= MEM) sl = 0;
                }
                errdotS[bb][lane] = s;
            }
        }
        __syncthreads();   // B2

        // ---- Section 2b: stream m=1..19 (waves 1-7) || register tail (wave 0) ----
        if (wv >= 1) {
            int kt = (wv - 1) * 11;
            int ktEnd = kt + 11; if (ktEnd > 76) ktEnd = 76;
            v4f c0 = {0.f,0.f,0.f,0.f}, c1 = {0.f,0.f,0.f,0.f};
            v4f c2 = {0.f,0.f,0.f,0.f}, c3 = {0.f,0.f,0.f,0.f};
            size_t tb = (size_t)(4 + kt) * 256 + lane;
            v8h pA0 = Wb[tb], pA1 = Wb[tb + 64], pA2 = Wb[tb + 128], pA3 = Wb[tb + 192];
            int m0 = 1 + (kt >> 2), kc0 = kt & 3;
            int s0 = head + m0 - 1; if (s0 >= MEM) s0 -= MEM;
            v8h pB = *(const v8h*)&RING(bb4, s0, kc0 * 32 + quad * 8);
            #pragma unroll 1
            for (; kt < ktEnd; ++kt) {
                v8h A0 = pA0, A1 = pA1, A2 = pA2, A3 = pA3, B = pB;
                int kn = kt + 1;
                if (kn < ktEnd) {
                    size_t tn = (size_t)(4 + kn) * 256 + lane;
                    pA0 = Wb[tn]; pA1 = Wb[tn + 64]; pA2 = Wb[tn + 128]; pA3 = Wb[tn + 192];
                    int mn = 1 + (kn >> 2), kcn = kn & 3;
                    int sn = head + mn - 1; if (sn >= MEM) sn -= MEM;
                    pB = *(const v8h*)&RING(bb4, sn, kcn * 32 + quad * 8);
                }
                c0 = mfma16(A0, B, c0);
                c1 = mfma16(A1, B, c1);
                c2 = mfma16(A2, B, c2);
                c3 = mfma16(A3, B, c3);
            }
            if (nn < 4) {
                *(v4f*)&red[np][wv][nn][ 0 + quad * 4] = c0;
                *(v4f*)&red[np][wv][nn][16 + quad * 4] = c1;
                *(v4f*)&red[np][wv][nn][32 + quad * 4] = c2;
                *(v4f*)&red[np][wv][nn][48 + quad * 4] = c3;
            }
        } else {
            // ================= wave-0 tail (register pipeline) =================
            // early operand prefetch (static addresses; overlap E1F/MFMAs)
            v8h w2a = W2Fv[lane], w2b = W2Fv[64 + lane];
            v8h agA0 = WaGv[0 * 64 + lane], agA1 = WaGv[1 * 64 + lane];
            v8h agA2 = WaGv[2 * 64 + lane], agA3 = WaGv[3 * 64 + lane];
            v4f bI0 = *(const v4f*)&ba_l[0][ 0 + quad * 4];
            v4f bF0 = *(const v4f*)&ba_l[0][16 + quad * 4];
            v4f bG0 = *(const v4f*)&ba_l[0][32 + quad * 4];
            v4f bO0 = *(const v4f*)&ba_l[0][48 + quad * 4];
            float theta = thS[bb4];
            v4f oA = *(const v4f*)&oS[bb4][0], oB = *(const v4f*)&oS[bb4][4];

            // E1F -> e1B f16 (inputs written in 2a)
            {
                float r0 = fmaxf(v0 + errdotS[0][lane]
                       + red0[0][0][lane] + red0[1][0][lane] + red0[2][0][lane] + red0[3][0][lane], 0.f);
                float r1 = fmaxf(v1 + errdotS[1][lane]
                       + red0[0][1][lane] + red0[1][1][lane] + red0[2][1][lane] + red0[3][1][lane], 0.f);
                float r2 = fmaxf(v2 + errdotS[2][lane]
                       + red0[0][2][lane] + red0[1][2][lane] + red0[2][2][lane] + red0[3][2][lane], 0.f);
                float r3 = fmaxf(v3 + errdotS[3][lane]
                       + red0[0][3][lane] + red0[1][3][lane] + red0[2][3][lane] + red0[3][3][lane], 0.f);
                e1B[0][lane] = (_Float16)r0;
                e1B[1][lane] = (_Float16)r1;
                e1B[2][lane] = (_Float16)r2;
                e1B[3][lane] = (_Float16)r3;
            }
            // ai = relu(W2 . e1 + b2): 2 chained MFMA (e1B LDS transpose kept)
            v8h bk0 = *(const v8h*)&e1B[bb4][quad * 8];
            v8h bk1 = *(const v8h*)&e1B[bb4][32 + quad * 8];
            v4f z4 = {0.f, 0.f, 0.f, 0.f};
            v4f cai = mfma16(w2a, bk0, b2v);
            cai = mfma16(w2b, bk1, cai);
            v4h av;
            #pragma unroll
            for (int r = 0; r < 4; ++r) av[r] = (_Float16)fmaxf(cai[r], 0.f);

            // bpermute geometry: dest lane (quad,nn) k-run = 8*quad..+7;
            // sources = lanes nn+32*(quad&1) and +16 (low quads: fresh input,
            // high quads: prev-step hidden from registers)
            const int idxA4 = (nn + ((quad & 1) << 5)) << 2;
            const int idxB4 = idxA4 + 64;
            const bool lowq = (quad < 2);

            // --- agent layer 0: B = [ai | h0_prev] ---
            v2i avd = __builtin_bit_cast(v2i, av);
            int tiA0 = bperm(idxA4, avd.x), tiA1 = bperm(idxA4, avd.y);
            int tiB0 = bperm(idxB4, avd.x), tiB1 = bperm(idxB4, avd.y);
            int thA0 = bperm(idxA4, h0p.x), thA1 = bperm(idxA4, h0p.y);
            int thB0 = bperm(idxB4, h0p.x), thB1 = bperm(idxB4, h0p.y);
            v4i wB0;
            wB0[0] = lowq ? tiA0 : thA0;
            wB0[1] = lowq ? tiA1 : thA1;
            wB0[2] = lowq ? tiB0 : thB0;
            wB0[3] = lowq ? tiB1 : thB1;
            v8h bf0 = __builtin_bit_cast(v8h, wB0);
            v4f zi = mfma16(agA0, bf0, z4);
            v4f zf = mfma16(agA1, bf0, z4);
            v4f zg = mfma16(agA2, bf0, z4);
            v4f zo = mfma16(agA3, bf0, z4);
            // prefetch later-stage operands while MFMAs run
            v8h agA4 = WaGv[4 * 64 + lane], agA5 = WaGv[5 * 64 + lane];
            v8h agA6 = WaGv[6 * 64 + lane], agA7 = WaGv[7 * 64 + lane];
            v4f bI1 = *(const v4f*)&ba_l[1][ 0 + quad * 4];
            v4f bF1 = *(const v4f*)&ba_l[1][16 + quad * 4];
            v4f bG1 = *(const v4f*)&ba_l[1][32 + quad * 4];
            v4f bO1 = *(const v4f*)&ba_l[1][48 + quad * 4];
            const int cbb = lane >> 4, chh = lane & 15;
            float nhp0 = nhS[0][cbb][chh], nhp1 = nhS[1][cbb][chh];
            float nhp2 = nhS[2][cbb][chh], nhp3 = nhS[3][cbb][chh];
            float nhp4 = nhS[4][cbb][chh], nhp5 = nhS[5][cbb][chh];
            float nhp6 = nhS[6][cbb][chh], nhp7 = nhS[7][cbb][chh];
            float ncp0 = ncS[0][cbb][chh], ncp1 = ncS[1][cbb][chh];
            float ncp2 = ncS[2][cbb][chh], ncp3 = ncS[3][cbb][chh];
            float ncp4 = ncS[4][cbb][chh], ncp5 = ncS[5][cbb][chh];
            float ncp6 = ncS[6][cbb][chh], ncp7 = ncS[7][cbb][chh];
            v4f wg0 = *(const v4f*)&Wg_l[0][quad * 4], wg1 = *(const v4f*)&Wg_l[1][quad * 4];
            v4f wg2 = *(const v4f*)&Wg_l[2][quad * 4], wg3 = *(const v4f*)&Wg_l[3][quad * 4];
            v4f wg4 = *(const v4f*)&Wg_l[4][quad * 4], wg5 = *(const v4f*)&Wg_l[5][quad * 4];
            v4f wg6 = *(const v4f*)&Wg_l[6][quad * 4], wg7 = *(const v4f*)&Wg_l[7][quad * 4];
            float bg0 = bg_l[0], bg1 = bg_l[1], bg2 = bg_l[2], bg3 = bg_l[3];
            float bg4 = bg_l[4], bg5 = bg_l[5], bg6 = bg_l[6], bg7 = bg_l[7];
            // act0 (replicated, ac0 in registers)
            v4h hr0;
            #pragma unroll
            for (int r = 0; r < 4; ++r) {
                float zi_ = zi[r] + bI0[r], zf_ = zf[r] + bF0[r];
                float zg_ = zg[r] + bG0[r], zo_ = zo[r] + bO0[r];
                float c2 = sigm(zf_) * ac0[r] + sigm(zi_) * tanh_f(zg_);
                ac0[r] = c2;
                hr0[r] = (_Float16)(sigm(zo_) * tanh_f(c2));
            }
            v2i h0n = __builtin_bit_cast(v2i, hr0);

            // --- agent layer 1: B = [h0_new | h1_prev] ---
            int uiA0 = bperm(idxA4, h0n.x), uiA1 = bperm(idxA4, h0n.y);
            int uiB0 = bperm(idxB4, h0n.x), uiB1 = bperm(idxB4, h0n.y);
            int uhA0 = bperm(idxA4, h1p.x), uhA1 = bperm(idxA4, h1p.y);
            int uhB0 = bperm(idxB4, h1p.x), uhB1 = bperm(idxB4, h1p.y);
            v4i wB1;
            wB1[0] = lowq ? uiA0 : uhA0;
            wB1[1] = lowq ? uiA1 : uhA1;
            wB1[2] = lowq ? uiB0 : uhB0;
            wB1[3] = lowq ? uiB1 : uhB1;
            v8h bf1 = __builtin_bit_cast(v8h, wB1);
            v4f yi = mfma16(agA4, bf1, z4);
            v4f yf = mfma16(agA5, bf1, z4);
            v4f yg = mfma16(agA6, bf1, z4);
            v4f yo = mfma16(agA7, bf1, z4);
            h0p = h0n;
            // act1
            v4h hr1; v4f hf;
            #pragma unroll
            for (int r = 0; r < 4; ++r) {
                float yi_ = yi[r] + bI1[r], yf_ = yf[r] + bF1[r];
                float yg_ = yg[r] + bG1[r], yo_ = yo[r] + bO1[r];
                float c2 = sigm(yf_) * ac1[r] + sigm(yi_) * tanh_f(yg_);
                ac1[r] = c2;
                float hv = sigm(yo_) * tanh_f(c2);
                hf[r] = hv; hr1[r] = (_Float16)hv;
            }
            h1p = __builtin_bit_cast(v2i, hr1);

            // --- gate: per-lane partial dot + shfl reduce + in-reg softmax ---
            float p0 = wg0[0]*hf[0] + wg0[1]*hf[1] + wg0[2]*hf[2] + wg0[3]*hf[3];
            float p1 = wg1[0]*hf[0] + wg1[1]*hf[1] + wg1[2]*hf[2] + wg1[3]*hf[3];
            float p2 = wg2[0]*hf[0] + wg2[1]*hf[1] + wg2[2]*hf[2] + wg2[3]*hf[3];
            float p3 = wg3[0]*hf[0] + wg3[1]*hf[1] + wg3[2]*hf[2] + wg3[3]*hf[3];
            float p4 = wg4[0]*hf[0] + wg4[1]*hf[1] + wg4[2]*hf[2] + wg4[3]*hf[3];
            float p5 = wg5[0]*hf[0] + wg5[1]*hf[1] + wg5[2]*hf[2] + wg5[3]*hf[3];
            float p6 = wg6[0]*hf[0] + wg6[1]*hf[1] + wg6[2]*hf[2] + wg6[3]*hf[3];
            float p7 = wg7[0]*hf[0] + wg7[1]*hf[1] + wg7[2]*hf[2] + wg7[3]*hf[3];
            p0 += __shfl_xor(p0, 16); p0 += __shfl_xor(p0, 32);
            p1 += __shfl_xor(p1, 16); p1 += __shfl_xor(p1, 32);
            p2 += __shfl_xor(p2, 16); p2 += __shfl_xor(p2, 32);
            p3 += __shfl_xor(p3, 16); p3 += __shfl_xor(p3, 32);
            p4 += __shfl_xor(p4, 16); p4 += __shfl_xor(p4, 32);
            p5 += __shfl_xor(p5, 16); p5 += __shfl_xor(p5, 32);
            p6 += __shfl_xor(p6, 16); p6 += __shfl_xor(p6, 32);
            p7 += __shfl_xor(p7, 16); p7 += __shfl_xor(p7, 32);
            p0 += bg0; p1 += bg1; p2 += bg2; p3 += bg3;
            p4 += bg4; p5 += bg5; p6 += bg6; p7 += bg7;
            float mx = fmaxf(fmaxf(fmaxf(p0, p1), fmaxf(p2, p3)),
                             fmaxf(fmaxf(p4, p5), fmaxf(p6, p7)));
            float e0 = __expf(p0 - mx), e1 = __expf(p1 - mx), e2 = __expf(p2 - mx), e3 = __expf(p3 - mx);
            float e4 = __expf(p4 - mx), e5 = __expf(p5 - mx), e6 = __expf(p6 - mx), e7 = __expf(p7 - mx);
            float sum = ((e0 + e1) + (e2 + e3)) + ((e4 + e5) + (e6 + e7));
            float inv = 1.0f / sum;
            float omt = 1.f - theta;
            gS0 = e0 * inv * theta + gS0 * omt;
            gS1 = e1 * inv * theta + gS1 * omt;
            gS2 = e2 * inv * theta + gS2 * omt;
            gS3 = e3 * inv * theta + gS3 * omt;
            gS4 = e4 * inv * theta + gS4 * omt;
            gS5 = e5 * inv * theta + gS5 * omt;
            gS6 = e6 * inv * theta + gS6 * omt;
            gS7 = e7 * inv * theta + gS7 * omt;

            // --- combine: pull batch-cbb gates via bpermute ---
            {
                const int gi = cbb << 2;
                float g0 = __int_as_float(bperm(gi, __float_as_int(gS0)));
                float g1 = __int_as_float(bperm(gi, __float_as_int(gS1)));
                float g2 = __int_as_float(bperm(gi, __float_as_int(gS2)));
                float g3 = __int_as_float(bperm(gi, __float_as_int(gS3)));
                float g4 = __int_as_float(bperm(gi, __float_as_int(gS4)));
                float g5 = __int_as_float(bperm(gi, __float_as_int(gS5)));
                float g6 = __int_as_float(bperm(gi, __float_as_int(gS6)));
                float g7 = __int_as_float(bperm(gi, __float_as_int(gS7)));
                float se = g0 * nhp0, sc = g0 * ncp0;
                se = fmaf(g1, nhp1, se); sc = fmaf(g1, ncp1, sc);
                se = fmaf(g2, nhp2, se); sc = fmaf(g2, ncp2, sc);
                se = fmaf(g3, nhp3, se); sc = fmaf(g3, ncp3, sc);
                se = fmaf(g4, nhp4, se); sc = fmaf(g4, ncp4, sc);
                se = fmaf(g5, nhp5, se); sc = fmaf(g5, ncp5, sc);
                se = fmaf(g6, nhp6, se); sc = fmaf(g6, ncp6, sc);
                se = fmaf(g7, nhp7, se); sc = fmaf(g7, ncp7, sc);
                ehH[cbb][chh] = (_Float16)se;
                ecS[cbb][chh] = sc;
            }
            // --- pred + output + next x slot (lanes 0-3 hold their batch's gates) ---
            if (lane < 4) {
                float s = gS0 * oA[0] + gS1 * oA[1] + gS2 * oA[2] + gS3 * oA[3]
                        + gS4 * oB[0] + gS5 * oB[1] + gS6 * oB[2] + gS7 * oB[3];
                predS[lane] = s;
                out[(b0 + lane) * S_LEN + t] = s;
                ehH[lane][16] = (_Float16)((t + 1 < S_LEN) ? xS[lane][t + 1] : 0.f);
            }
        }
        __syncthreads();   // B3
    }
}

extern "C" void kernel_launch(void* const* d_in, const int* in_sizes, int n_in,
                              void* d_out, int out_size, void* d_ws, size_t ws_size,
                              hipStream_t stream) {
    const float* xp    = (const float*)d_in[0];
    const float* pred0 = (const float*)d_in[1];
    const float* gate0 = (const float*)d_in[2];
    const float* W_ih  = (const float*)d_in[3];
    const float* W_hh  = (const float*)d_in[4];
    const float* b_ih  = (const float*)d_in[5];
    const float* b_hh  = (const float*)d_in[6];
    const float* W_o   = (const float*)d_in[7];
    const float* b_o   = (const float*)d_in[8];
    const float* W1    = (const float*)d_in[9];
    const float* b1    = (const float*)d_in[10];
    const float* W2    = (const float*)d_in[11];
    const float* b2    = (const float*)d_in[12];
    const float* Wg    = (const float*)d_in[13];
    const float* bg    = (const float*)d_in[14];
    const float* Wa_ih = (const float*)d_in[15];
    const float* Wa_hh = (const float*)d_in[16];
    const float* ba_ih = (const float*)d_in[17];
    const float* ba_hh = (const float*)d_in[18];
    _Float16* W1F  = (_Float16*)d_ws;                // 163840 f16
    _Float16* WAF  = W1F + 163840;                   // 16384
    _Float16* W2F  = WAF + 16384;                    // 1024
    _Float16* WAGF = W2F + 1024;                     // 4096

    prep_w<<<(163840 + 16384 + 1024 + 4096 + 255) / 256, 256, 0, stream>>>(
        W1, W_hh, W_ih, b_ih, b_hh, W2, Wa_ih, Wa_hh, W1F, WAF, W2F, WAGF);
    mmoe_kernel<<<512 / NB, NTHR, 0, stream>>>(
        xp, pred0, gate0, W_ih, W_hh, b_ih, b_hh, W_o, b_o,
        W1, b1, W2, b2, Wg, bg, Wa_ih, Wa_hh, ba_ih, ba_hh,
        W1F, WAF, W2F, WAGF, (float*)d_out);
}